// Round 4
// baseline (216.486 us; speedup 1.0000x reference)
//
#include <hip/hip_runtime.h>
#include <hip/hip_bf16.h>

#define NS     32768
#define NROWS  2048
#define HOP    127
#define NW     257
#define NB     128
#define WTILE  16
#define NT     17            // ceil(257/16); tile 16 has 1 valid window
#define TWOPI_255 0.02463994236f

typedef _Float16 f16;
typedef __attribute__((ext_vector_type(2))) _Float16 f16x2;
typedef __attribute__((ext_vector_type(8))) _Float16 f16x8;
typedef __attribute__((ext_vector_type(4))) float f32x4;

__device__ inline f32x4 load4u(const char* p) {  // 4B-aligned 16B load
    f32x4 v;
    __builtin_memcpy(&v, p, 16);
    return v;
}

// One block (4 waves) per row. Wave cq owns components [cq*64, cq*64+64):
// comps 0..127 = cos(f), 128..255 = sin(f-128). K folded 255->128 via
// y+[k]=x[k]+x[255-k], y-[k]=x[k]-x[255-k]. S[f]=(sum_w Ccos^2+Csin^2)/257.
__global__ __launch_bounds__(256, 4)
void psd_kernel(const float* __restrict__ X, float* __restrict__ out) {
    const int row  = blockIdx.x;
    const int tid  = threadIdx.x;
    const int lane = tid & 63;
    const int cq   = tid >> 6;
    const int r16  = lane & 15;
    const int kg   = lane >> 4;
    const int is_sin = cq >> 1;

    __shared__ alignas(16) f16 atile[2][WTILE * 256];  // 2 x 8 KB, XOR-swizzled
    __shared__ float scol[256];

    const char* __restrict__ xrow = (const char*)(X + (size_t)row * NS);

    const int sw  = tid >> 4;           // staging window 0..15 within tile
    const int sk0 = (tid & 15) * 8;     // staging k-octet base

    // per-lane loop-invariant global byte offsets (tile-local)
    const uint voff_fwd = (uint)((sw * HOP + sk0) * 4);
    const uint voff_rev = (uint)((sw * HOP + 248 - sk0) * 4);
    const uint vclamp   = (uint)((NS - 4) * 4);   // max safe 16B-load byte offset

    // ---- tile-0 loads (issued before B-gen; vmcnt drains under it) ----
    f32x4 fva = load4u(xrow + voff_fwd);
    f32x4 fvb = load4u(xrow + voff_fwd + 16);
    f32x4 rva = load4u(xrow + voff_rev);
    f32x4 rvb = load4u(xrow + voff_rev + 16);

    // ---- folded DFT basis in registers: 64 VGPRs per wave ----
    f16x8 bfrag[4][4];
    #pragma unroll
    for (int nt = 0; nt < 4; ++nt) {
        const int comp = cq * 64 + nt * 16 + r16;
        const int f    = comp & 127;
        #pragma unroll
        for (int kk = 0; kk < 4; ++kk) {
            int m = (f * (kk * 32 + kg * 8)) % 255;
            f16x8 v;
            #pragma unroll
            for (int j = 0; j < 8; ++j) {
                const float ang = (float)m * TWOPI_255;
                v[j] = (f16)(is_sin ? __sinf(ang) : __cosf(ang));
                m += f; if (m >= 255) m -= 255;
            }
            bfrag[nt][kk] = v;
        }
    }

    // ---- hoisted LDS byte offsets ----
    const uint swz  = (uint)((sw & 7) << 4);
    const uint wr0  = (uint)(sw * 512 + sk0 * 2) ^ swz;          // y+ half
    const uint wr1  = (uint)(sw * 512 + sk0 * 2 + 256) ^ swz;    // y- half
    const uint rswz = (uint)((r16 & 7) << 4);
    uint rd[4];
    #pragma unroll
    for (int kk = 0; kk < 4; ++kk)
        rd[kk] = (uint)(r16 * 512 + is_sin * 256 + kg * 16 + kk * 64) ^ rswz;

    char* const lds = (char*)&atile[0][0];

    auto fold_write = [&](uint bufoff, bool valid) {
        float yp[8], ym[8];
        #pragma unroll
        for (int j = 0; j < 8; ++j) {
            const float fj = (j < 4) ? fva[j] : fvb[j - 4];
            const int   pi = 7 - j;                      // partner x[b+255-(sk0+j)]
            const float rj = (pi < 4) ? rva[pi] : rvb[pi - 4];
            yp[j] = fj + rj;
            ym[j] = fj - rj;
        }
        if (sk0 == 0) { yp[0] = fva[0]; ym[0] = 0.0f; }  // k=0 pairs with zero pad
        f16x8 h0, h1;
        #pragma unroll
        for (int q = 0; q < 4; ++q) {
            f16x2 pp = __builtin_bit_cast(f16x2, __builtin_amdgcn_cvt_pkrtz(yp[2*q], yp[2*q+1]));
            f16x2 pm = __builtin_bit_cast(f16x2, __builtin_amdgcn_cvt_pkrtz(ym[2*q], ym[2*q+1]));
            h0[2*q] = pp[0]; h0[2*q+1] = pp[1];
            h1[2*q] = pm[0]; h1[2*q+1] = pm[1];
        }
        if (!valid) {
            #pragma unroll
            for (int q = 0; q < 8; ++q) { h0[q] = (f16)0.0f; h1[q] = (f16)0.0f; }
        }
        *(f16x8*)(lds + bufoff + wr0) = h0;
        *(f16x8*)(lds + bufoff + wr1) = h1;
    };

    // prologue: fold tile 0, then issue tile-1 loads (full-iter latency cover)
    fold_write(0u, true);
    {
        const uint ub = (uint)(1 * WTILE * HOP * 4);
        fva = load4u(xrow + (voff_fwd + ub));
        fvb = load4u(xrow + (voff_fwd + ub + 16));
        rva = load4u(xrow + (voff_rev + ub));
        rvb = load4u(xrow + (voff_rev + ub + 16));
    }
    __syncthreads();

    float ssum[4] = {0.f, 0.f, 0.f, 0.f};

    #pragma unroll 2
    for (int mt = 0; mt < NT; ++mt) {
        const uint bo_cur = (mt & 1) ? 8192u : 0u;
        const uint bo_nxt = bo_cur ^ 8192u;

        // MFMA over current tile
        f32x4 acc0 = {0,0,0,0}, acc1 = {0,0,0,0}, acc2 = {0,0,0,0}, acc3 = {0,0,0,0};
        __builtin_amdgcn_s_setprio(1);
        #pragma unroll
        for (int kk = 0; kk < 4; ++kk) {
            const f16x8 af = *(const f16x8*)(lds + bo_cur + rd[kk]);
            acc0 = __builtin_amdgcn_mfma_f32_16x16x32_f16(af, bfrag[0][kk], acc0, 0, 0, 0);
            acc1 = __builtin_amdgcn_mfma_f32_16x16x32_f16(af, bfrag[1][kk], acc1, 0, 0, 0);
            acc2 = __builtin_amdgcn_mfma_f32_16x16x32_f16(af, bfrag[2][kk], acc2, 0, 0, 0);
            acc3 = __builtin_amdgcn_mfma_f32_16x16x32_f16(af, bfrag[3][kk], acc3, 0, 0, 0);
        }
        __builtin_amdgcn_s_setprio(0);
        #pragma unroll
        for (int r = 0; r < 4; ++r) {
            ssum[0] += acc0[r] * acc0[r];
            ssum[1] += acc1[r] * acc1[r];
            ssum[2] += acc2[r] * acc2[r];
            ssum[3] += acc3[r] * acc3[r];
        }

        // fold+write tile mt+1 (loads were issued one full iteration ago)
        if (mt < NT - 1) {
            const bool valid = (mt != 15) || (sw == 0);  // tile 16: only window 256 valid
            fold_write(bo_nxt, valid);
        }
        // issue loads for tile mt+2 (clamped; pad-window data zeroed at fold)
        if (mt < NT - 2) {
            const uint ub = (uint)((mt + 2) * WTILE * HOP * 4);
            const uint f0 = min(voff_fwd + ub,      vclamp);
            const uint f1 = min(voff_fwd + ub + 16, vclamp);
            const uint r0 = min(voff_rev + ub,      vclamp);
            const uint r1 = min(voff_rev + ub + 16, vclamp);
            fva = load4u(xrow + f0);
            fvb = load4u(xrow + f1);
            rva = load4u(xrow + r0);
            rvb = load4u(xrow + r1);
        }
        __syncthreads();
    }

    // ---- reduce over k-groups; D col = lane&15 ----
    #pragma unroll
    for (int nt = 0; nt < 4; ++nt) {
        float v = ssum[nt];
        v += __shfl_xor(v, 16, 64);
        v += __shfl_xor(v, 32, 64);
        if (kg == 0) scol[cq * 64 + nt * 16 + r16] = v;
    }
    __syncthreads();
    if (tid < NB) {
        out[(size_t)row * NB + tid] = (scol[tid] + scol[tid + NB]) * (1.0f / 257.0f);
    }
}

extern "C" void kernel_launch(void* const* d_in, const int* in_sizes, int n_in,
                              void* d_out, int out_size, void* d_ws, size_t ws_size,
                              hipStream_t stream) {
    const float* X = (const float*)d_in[0];
    float* out = (float*)d_out;
    (void)in_sizes; (void)n_in; (void)d_ws; (void)ws_size; (void)out_size;
    psd_kernel<<<dim3(NROWS), dim3(256), 0, stream>>>(X, out);
}

// Round 5
// 65.089 us; speedup vs baseline: 3.3260x; 3.3260x over previous
//
#include <hip/hip_runtime.h>
#include <hip/hip_bf16.h>

#define NS     32768
#define NROWS  2048
#define HOP    127
#define NW     257
#define NB     128
#define WTILE  16
#define NT     17            // ceil(257/16); tile 16 has 1 valid window
#define TWOPI_255 0.02463994236f   // 2*pi/255

typedef _Float16 f16;
typedef __attribute__((ext_vector_type(8))) _Float16 f16x8;
typedef __attribute__((ext_vector_type(4))) float f32x4;

__device__ inline f32x4 load4u(const float* p) {  // 4B-aligned 16B load
    f32x4 v;
    __builtin_memcpy(&v, p, 16);
    return v;
}

// One block (4 waves) per row. Wave cq owns components [cq*64, cq*64+64):
// comps 0..127 = cos(f), 128..255 = sin(f-128). K folded 255->128 via
// y+[k]=x[k]+x[255-k], y-[k]=x[k]-x[255-k]. S[f]=(sum_w Ccos^2+Csin^2)/257.
__global__ __launch_bounds__(256, 4)
void psd_kernel(const float* __restrict__ X, float* __restrict__ out) {
    const int row  = blockIdx.x;
    const int tid  = threadIdx.x;
    const int lane = tid & 63;
    const int cq   = tid >> 6;      // wave id
    const int r16  = lane & 15;
    const int kg   = lane >> 4;
    const int is_sin = cq >> 1;     // waves 2,3 -> sin half

    __shared__ alignas(16) f16 atile[2][WTILE * 256];  // 2 x 8 KB, XOR-swizzled
    __shared__ float scol[256];

    const float* __restrict__ xrow = X + (size_t)row * NS;

    const int sw  = tid >> 4;           // staging window 0..15 within tile
    const int sk0 = (tid & 15) * 8;     // staging k-octet base

    // ---- issue tile-0 loads early (hide under B-gen) ----
    f32x4 fva, fvb, rva, rvb;
    {
        const int b = sw * HOP;                       // tile 0 always valid
        fva = load4u(xrow + b + sk0);
        fvb = load4u(xrow + b + sk0 + 4);
        rva = load4u(xrow + b + 248 - sk0);
        rvb = load4u(xrow + b + 252 - sk0);
    }

    // ---- generate folded DFT basis: 64 VGPRs resident per wave ----
    f16x8 bfrag[4][4];
    #pragma unroll
    for (int nt = 0; nt < 4; ++nt) {
        const int comp = cq * 64 + nt * 16 + r16;
        const int f    = comp & 127;
        #pragma unroll
        for (int kk = 0; kk < 4; ++kk) {
            int m = (f * (kk * 32 + kg * 8)) % 255;   // one mod per frag
            f16x8 v;
            #pragma unroll
            for (int j = 0; j < 8; ++j) {
                const float ang = (float)m * TWOPI_255;
                const float s   = is_sin ? __sinf(ang) : __cosf(ang);
                v[j] = (f16)s;
                m += f; if (m >= 255) m -= 255;       // incremental phase
            }
            bfrag[nt][kk] = v;
        }
    }

    // ---- fold + write helper ----
    const f16x8 z8 = {(f16)0,(f16)0,(f16)0,(f16)0,(f16)0,(f16)0,(f16)0,(f16)0};
    auto fold_write = [&](int buf, bool valid) {
        float yp[8], ym[8];
        #pragma unroll
        for (int j = 0; j < 8; ++j) {
            const float fj = (j < 4) ? fva[j] : fvb[j - 4];
            const int   pi = 7 - j;                     // partner x[b+255-(sk0+j)]
            const float rj = (pi < 4) ? rva[pi] : rvb[pi - 4];
            yp[j] = fj + rj;
            ym[j] = fj - rj;
        }
        if (sk0 == 0) { yp[0] = fva[0]; ym[0] = 0.0f; }  // k=0 pairs with zero pad
        f16x8 h0, h1;
        #pragma unroll
        for (int j = 0; j < 8; ++j) { h0[j] = (f16)yp[j]; h1[j] = (f16)ym[j]; }
        if (!valid) { h0 = z8; h1 = z8; }
        char* wp = (char*)&atile[buf][0];
        const uint sb  = (uint)(sw * 512 + sk0 * 2);
        const uint swz = (uint)((sw & 7) << 4);
        *(f16x8*)(wp + (sb ^ swz))         = h0;        // y+ half
        *(f16x8*)(wp + ((sb + 256) ^ swz)) = h1;        // y- half
    };

    // prologue: fold tile 0, then issue tile-1 loads
    fold_write(0, true);
    {
        const int b = (WTILE + sw) * HOP;
        fva = load4u(xrow + b + sk0);
        fvb = load4u(xrow + b + sk0 + 4);
        rva = load4u(xrow + b + 248 - sk0);
        rvb = load4u(xrow + b + 252 - sk0);
    }
    __syncthreads();

    float ssum[4] = {0.f, 0.f, 0.f, 0.f};
    const uint rswz  = (uint)((r16 & 7) << 4);
    const uint rbase = (uint)(r16 * 512 + is_sin * 256 + kg * 16);

    for (int mt = 0; mt < NT; ++mt) {
        const int cur = mt & 1;

        // MFMA over current tile
        const char* ap = (const char*)&atile[cur][0];
        f32x4 acc0 = {0,0,0,0}, acc1 = {0,0,0,0}, acc2 = {0,0,0,0}, acc3 = {0,0,0,0};
        __builtin_amdgcn_s_setprio(1);
        #pragma unroll
        for (int kk = 0; kk < 4; ++kk) {
            const f16x8 af = *(const f16x8*)(ap + ((rbase + (uint)(kk * 64)) ^ rswz));
            acc0 = __builtin_amdgcn_mfma_f32_16x16x32_f16(af, bfrag[0][kk], acc0, 0, 0, 0);
            acc1 = __builtin_amdgcn_mfma_f32_16x16x32_f16(af, bfrag[1][kk], acc1, 0, 0, 0);
            acc2 = __builtin_amdgcn_mfma_f32_16x16x32_f16(af, bfrag[2][kk], acc2, 0, 0, 0);
            acc3 = __builtin_amdgcn_mfma_f32_16x16x32_f16(af, bfrag[3][kk], acc3, 0, 0, 0);
        }
        __builtin_amdgcn_s_setprio(0);
        #pragma unroll
        for (int r = 0; r < 4; ++r) {
            ssum[0] += acc0[r] * acc0[r];
            ssum[1] += acc1[r] * acc1[r];
            ssum[2] += acc2[r] * acc2[r];
            ssum[3] += acc3[r] * acc3[r];
        }

        // fold+write tile mt+1 (its loads were issued one iteration ago)
        if (mt < NT - 1) {
            const bool valid = ((mt + 1) * WTILE + sw) < NW;  // tile 16: only sw==0
            fold_write(cur ^ 1, valid);
        }
        // issue loads for tile mt+2 (full iteration of latency cover)
        if (mt < NT - 2) {
            const int w = (mt + 2) * WTILE + sw;
            int b = w * HOP; if (b > NS - 256) b = NS - 256;   // clamp pad windows
            fva = load4u(xrow + b + sk0);
            fvb = load4u(xrow + b + sk0 + 4);
            rva = load4u(xrow + b + 248 - sk0);
            rvb = load4u(xrow + b + 252 - sk0);
        }
        __syncthreads();   // dbuf write/read ordering
    }

    // ---- reduce over k-groups; each comp owned by exactly one wave ----
    #pragma unroll
    for (int nt = 0; nt < 4; ++nt) {
        float v = ssum[nt];
        v += __shfl_xor(v, 16, 64);
        v += __shfl_xor(v, 32, 64);
        if (kg == 0) scol[cq * 64 + nt * 16 + r16] = v;
    }
    __syncthreads();
    if (tid < NB) {
        out[(size_t)row * NB + tid] = (scol[tid] + scol[tid + NB]) * (1.0f / 257.0f);
    }
}

extern "C" void kernel_launch(void* const* d_in, const int* in_sizes, int n_in,
                              void* d_out, int out_size, void* d_ws, size_t ws_size,
                              hipStream_t stream) {
    const float* X = (const float*)d_in[0];
    float* out = (float*)d_out;
    (void)in_sizes; (void)n_in; (void)d_ws; (void)ws_size; (void)out_size;
    psd_kernel<<<dim3(NROWS), dim3(256), 0, stream>>>(X, out);
}

// Round 6
// 61.828 us; speedup vs baseline: 3.5014x; 1.0527x over previous
//
#include <hip/hip_runtime.h>
#include <hip/hip_bf16.h>

#define NS     32768
#define NROWS  2048
#define HOP    127
#define NW     257
#define NB     128
#define WTILE  16
#define NT     17            // ceil(257/16); tile 16 has 1 valid window
#define TWOPI_255 0.02463994236f   // 2*pi/255

typedef _Float16 f16;
typedef __attribute__((ext_vector_type(2))) _Float16 f16x2;
typedef __attribute__((ext_vector_type(8))) _Float16 f16x8;
typedef __attribute__((ext_vector_type(4))) float f32x4;

__device__ inline f32x4 load4u(const float* p) {  // 4B-aligned 16B load
    f32x4 v;
    __builtin_memcpy(&v, p, 16);
    return v;
}

// One block (4 waves) per row. Wave cq owns components [cq*64, cq*64+64):
// comps 0..127 = cos(f), 128..255 = sin(f-128). K folded 255->128 via
// y+[k]=x[k]+x[255-k], y-[k]=x[k]-x[255-k]. S[f]=(sum_w Ccos^2+Csin^2)/257.
//
// Pipeline per iteration (1 raw barrier, loads live across it):
//   fold_write(t+1) -> issue loads(t+2) -> lgkmcnt(0) -> s_barrier ->
//   ds_read frags(t+1) into anxt -> MFMA(acur = tile t) -> swap.
__global__ __launch_bounds__(256, 3)
void psd_kernel(const float* __restrict__ X, float* __restrict__ out) {
    const int row  = blockIdx.x;
    const int tid  = threadIdx.x;
    const int lane = tid & 63;
    const int cq   = tid >> 6;      // wave id
    const int r16  = lane & 15;
    const int kg   = lane >> 4;
    const int is_sin = cq >> 1;     // waves 2,3 -> sin half

    __shared__ alignas(16) f16 atile[2][WTILE * 256];  // 2 x 8 KB, XOR-swizzled
    __shared__ float scol[256];

    const float* __restrict__ xrow = X + (size_t)row * NS;

    const int sw  = tid >> 4;           // staging window 0..15 within tile
    const int sk0 = (tid & 15) * 8;     // staging k-octet base

    // ---- issue tile-0 loads early (hide under B-gen) ----
    f32x4 fva, fvb, rva, rvb;
    {
        const int b = sw * HOP;                       // tile 0 always valid
        fva = load4u(xrow + b + sk0);
        fvb = load4u(xrow + b + sk0 + 4);
        rva = load4u(xrow + b + 248 - sk0);
        rvb = load4u(xrow + b + 252 - sk0);
    }

    // ---- generate folded DFT basis: 64 VGPRs resident per wave ----
    f16x8 bfrag[4][4];
    #pragma unroll
    for (int nt = 0; nt < 4; ++nt) {
        const int comp = cq * 64 + nt * 16 + r16;
        const int f    = comp & 127;
        #pragma unroll
        for (int kk = 0; kk < 4; ++kk) {
            int m = (f * (kk * 32 + kg * 8)) % 255;   // one mod per frag
            f16x8 v;
            #pragma unroll
            for (int j = 0; j < 8; ++j) {
                const float ang = (float)m * TWOPI_255;
                const float s   = is_sin ? __sinf(ang) : __cosf(ang);
                v[j] = (f16)s;
                m += f; if (m >= 255) m -= 255;       // incremental phase
            }
            bfrag[nt][kk] = v;
        }
    }

    char* const lds = (char*)&atile[0][0];

    // hoisted LDS byte offsets
    const uint swz = (uint)((sw & 7) << 4);
    const uint wr0 = ((uint)(sw * 512 + sk0 * 2)) ^ swz;          // y+ half
    const uint wr1 = ((uint)(sw * 512 + sk0 * 2 + 256)) ^ swz;    // y- half
    const uint rswz = (uint)((r16 & 7) << 4);
    uint rd[4];
    #pragma unroll
    for (int kk = 0; kk < 4; ++kk)
        rd[kk] = ((uint)(r16 * 512 + is_sin * 256 + kg * 16 + kk * 64)) ^ rswz;

    // ---- packed fold + LDS write (f16 pk add/sub; tolerance >> pk rounding) ----
    auto fold_write = [&](char* wp, bool valid) {
        f16x8 h0, h1;
        #pragma unroll
        for (int q = 0; q < 4; ++q) {
            const int j0 = 2 * q, j1 = 2 * q + 1;
            const float f0 = (j0 < 4) ? fva[j0] : fvb[j0 - 4];
            const float f1 = (j1 < 4) ? fva[j1] : fvb[j1 - 4];
            // partner of j: x[b+255-(sk0+j)] = (j<4) ? rvb[3-j] : rva[7-j]
            const float r0 = (j0 < 4) ? rvb[3 - j0] : rva[7 - j0];
            const float r1 = (j1 < 4) ? rvb[3 - j1] : rva[7 - j1];
            const f16x2 fp = __builtin_bit_cast(f16x2, __builtin_amdgcn_cvt_pkrtz(f0, f1));
            const f16x2 rp = __builtin_bit_cast(f16x2, __builtin_amdgcn_cvt_pkrtz(r0, r1));
            const f16x2 s = fp + rp;
            const f16x2 d = fp - rp;
            h0[j0] = s[0]; h0[j1] = s[1];
            h1[j0] = d[0]; h1[j1] = d[1];
        }
        if (sk0 == 0) { h0[0] = (f16)fva[0]; h1[0] = (f16)0.0f; }  // k=0: zero-pad partner
        if (!valid) {
            #pragma unroll
            for (int j = 0; j < 8; ++j) { h0[j] = (f16)0.0f; h1[j] = (f16)0.0f; }
        }
        *(f16x8*)(wp + wr0) = h0;
        *(f16x8*)(wp + wr1) = h1;
    };

    // ---- prologue: fold tile 0, issue tile-1 loads, read tile-0 frags ----
    fold_write(lds, true);
    {
        const int b = (WTILE + sw) * HOP;
        fva = load4u(xrow + b + sk0);
        fvb = load4u(xrow + b + sk0 + 4);
        rva = load4u(xrow + b + 248 - sk0);
        rvb = load4u(xrow + b + 252 - sk0);
    }
    asm volatile("s_waitcnt lgkmcnt(0)" ::: "memory");
    __builtin_amdgcn_s_barrier();
    asm volatile("" ::: "memory");

    f16x8 acur[4], anxt[4];
    #pragma unroll
    for (int kk = 0; kk < 4; ++kk) acur[kk] = *(const f16x8*)(lds + rd[kk]);

    float ssum[4] = {0.f, 0.f, 0.f, 0.f};

    for (int mt = 0; mt < NT; ++mt) {
        if (mt < NT - 1) {
            char* wp = lds + (((mt + 1) & 1) << 13);
            const bool valid = ((mt + 1) * WTILE + sw) < NW;  // tile 16: only sw==0
            fold_write(wp, valid);
            if (mt < NT - 2) {   // issue loads for tile mt+2; live across barrier
                const int w = (mt + 2) * WTILE + sw;
                int b = w * HOP; if (b > NS - 256) b = NS - 256;   // clamp pad windows
                fva = load4u(xrow + b + sk0);
                fvb = load4u(xrow + b + sk0 + 4);
                rva = load4u(xrow + b + 248 - sk0);
                rvb = load4u(xrow + b + 252 - sk0);
            }
            asm volatile("s_waitcnt lgkmcnt(0)" ::: "memory");  // drain ds_writes only
            __builtin_amdgcn_s_barrier();
            asm volatile("" ::: "memory");
            const char* ap = lds + (((mt + 1) & 1) << 13);
            #pragma unroll
            for (int kk = 0; kk < 4; ++kk)        // prefetch next tile's A-frags
                anxt[kk] = *(const f16x8*)(ap + rd[kk]);
        }

        // MFMA on current tile (frags read one iteration ago)
        f32x4 acc0 = {0,0,0,0}, acc1 = {0,0,0,0}, acc2 = {0,0,0,0}, acc3 = {0,0,0,0};
        __builtin_amdgcn_s_setprio(1);
        #pragma unroll
        for (int kk = 0; kk < 4; ++kk) {
            acc0 = __builtin_amdgcn_mfma_f32_16x16x32_f16(acur[kk], bfrag[0][kk], acc0, 0, 0, 0);
            acc1 = __builtin_amdgcn_mfma_f32_16x16x32_f16(acur[kk], bfrag[1][kk], acc1, 0, 0, 0);
            acc2 = __builtin_amdgcn_mfma_f32_16x16x32_f16(acur[kk], bfrag[2][kk], acc2, 0, 0, 0);
            acc3 = __builtin_amdgcn_mfma_f32_16x16x32_f16(acur[kk], bfrag[3][kk], acc3, 0, 0, 0);
        }
        __builtin_amdgcn_s_setprio(0);
        #pragma unroll
        for (int r = 0; r < 4; ++r) {
            ssum[0] += acc0[r] * acc0[r];
            ssum[1] += acc1[r] * acc1[r];
            ssum[2] += acc2[r] * acc2[r];
            ssum[3] += acc3[r] * acc3[r];
        }

        if (mt < NT - 1) {
            #pragma unroll
            for (int kk = 0; kk < 4; ++kk) acur[kk] = anxt[kk];
        }
    }

    // ---- reduce over k-groups; each comp owned by exactly one wave ----
    #pragma unroll
    for (int nt = 0; nt < 4; ++nt) {
        float v = ssum[nt];
        v += __shfl_xor(v, 16, 64);
        v += __shfl_xor(v, 32, 64);
        if (kg == 0) scol[cq * 64 + nt * 16 + r16] = v;
    }
    __syncthreads();
    if (tid < NB) {
        out[(size_t)row * NB + tid] = (scol[tid] + scol[tid + NB]) * (1.0f / 257.0f);
    }
}

extern "C" void kernel_launch(void* const* d_in, const int* in_sizes, int n_in,
                              void* d_out, int out_size, void* d_ws, size_t ws_size,
                              hipStream_t stream) {
    const float* X = (const float*)d_in[0];
    float* out = (float*)d_out;
    (void)in_sizes; (void)n_in; (void)d_ws; (void)ws_size; (void)out_size;
    psd_kernel<<<dim3(NROWS), dim3(256), 0, stream>>>(X, out);
}

// Round 7
// 60.565 us; speedup vs baseline: 3.5744x; 1.0209x over previous
//
#include <hip/hip_runtime.h>
#include <hip/hip_bf16.h>

#define NS     32768
#define NROWS  2048
#define HOP    127
#define NW     257
#define NB     128
#define WTILE  16
#define NT     17            // ceil(257/16); tile 16 has 1 valid window
#define TWOPI_255 0.02463994236f   // 2*pi/255

typedef _Float16 f16;
typedef __attribute__((ext_vector_type(2))) _Float16 f16x2;
typedef __attribute__((ext_vector_type(4))) _Float16 f16x4;
typedef __attribute__((ext_vector_type(8))) _Float16 f16x8;
typedef __attribute__((ext_vector_type(4))) float f32x4;

__device__ inline f32x4 load4u(const char* p) {  // 4B-aligned 16B load
    f32x4 v;
    __builtin_memcpy(&v, p, 16);
    return v;
}

// One block (8 waves, 512 thr) per row. Wave cq owns 32 components:
// c = is_sin*128 + (cq&3)*32 + nt*16 + r16, nt=0,1. comps 0..127 = cos(f),
// 128..255 = sin(f). K folded 255->128 via y+[k]=x[k]+x[255-k],
// y-[k]=x[k]-x[255-k]. S[f] = (sum_w Ccos^2 + Csin^2)/257.
// 8 waves @ ~80 VGPR -> 6 waves/SIMD (3 blocks/CU, 75% occupancy): the pipe
// duty cycle per wave is ~25% MFMA; 6 staggered waves keep all pipes busy.
__global__ __launch_bounds__(512, 6)
void psd_kernel(const float* __restrict__ X, float* __restrict__ out) {
    const int row  = blockIdx.x;
    const int tid  = threadIdx.x;
    const int lane = tid & 63;
    const int cq   = tid >> 6;      // wave 0..7
    const int r16  = lane & 15;
    const int kg   = lane >> 4;
    const int is_sin = cq >> 2;     // waves 4..7 -> sin half

    __shared__ alignas(16) f16 atile[2][WTILE * 256];  // 2 x 8 KB, XOR-swizzled
    __shared__ float scol[256];

    const char* __restrict__ xrow = (const char*)(X + (size_t)row * NS);

    const int sw  = tid >> 5;           // staging window 0..15
    const int sq  = tid & 31;           // staging k-quad 0..31
    const int sk0 = sq * 4;

    // loop-invariant per-lane global byte offsets (tile-local)
    const uint voff_f = (uint)((sw * HOP + sk0) * 4);
    const uint voff_r = (uint)((sw * HOP + 252 - sk0) * 4);

    // ---- tile-0 loads (drain under basis-gen) ----
    f32x4 fv = load4u(xrow + voff_f);
    f32x4 rv = load4u(xrow + voff_r);

    // ---- folded DFT basis: 32 VGPRs per wave ----
    f16x8 bfrag[2][4];
    #pragma unroll
    for (int nt = 0; nt < 2; ++nt) {
        const int f = (cq & 3) * 32 + nt * 16 + r16;   // freq 0..127
        #pragma unroll
        for (int kk = 0; kk < 4; ++kk) {
            int m = (f * (kk * 32 + kg * 8)) % 255;
            f16x8 v;
            #pragma unroll
            for (int j = 0; j < 8; ++j) {
                const float ang = (float)m * TWOPI_255;
                v[j] = (f16)(is_sin ? __sinf(ang) : __cosf(ang));
                m += f; if (m >= 255) m -= 255;
            }
            bfrag[nt][kk] = v;
        }
    }

    char* const lds = (char*)&atile[0][0];

    // hoisted LDS byte offsets
    const uint swz  = (uint)((sw & 7) << 4);
    const uint wr_p = ((uint)(sw * 512 + sq * 8)) ^ swz;         // y+ (8B)
    const uint wr_m = ((uint)(sw * 512 + sq * 8 + 256)) ^ swz;   // y- (8B)
    const uint rswz = (uint)((r16 & 7) << 4);
    uint rd[4];
    #pragma unroll
    for (int kk = 0; kk < 4; ++kk)
        rd[kk] = ((uint)(r16 * 512 + is_sin * 256 + kg * 16 + kk * 64)) ^ rswz;

    // ---- packed fold (4 pairs) + 2 x ds_write_b64 ----
    auto fold_write = [&](char* wp, bool valid) {
        // partner of k=sk0+j is rv[3-j]
        const f16x2 fp01 = __builtin_bit_cast(f16x2, __builtin_amdgcn_cvt_pkrtz(fv[0], fv[1]));
        const f16x2 fp23 = __builtin_bit_cast(f16x2, __builtin_amdgcn_cvt_pkrtz(fv[2], fv[3]));
        const f16x2 rp01 = __builtin_bit_cast(f16x2, __builtin_amdgcn_cvt_pkrtz(rv[3], rv[2]));
        const f16x2 rp23 = __builtin_bit_cast(f16x2, __builtin_amdgcn_cvt_pkrtz(rv[1], rv[0]));
        const f16x2 yp01 = fp01 + rp01, yp23 = fp23 + rp23;
        const f16x2 ym01 = fp01 - rp01, ym23 = fp23 - rp23;
        f16x4 h0, h1;
        h0[0] = yp01[0]; h0[1] = yp01[1]; h0[2] = yp23[0]; h0[3] = yp23[1];
        h1[0] = ym01[0]; h1[1] = ym01[1]; h1[2] = ym23[0]; h1[3] = ym23[1];
        if (sq == 0) { h0[0] = (f16)fv[0]; h1[0] = (f16)0.0f; }  // k=0: pad partner
        if (!valid) {
            #pragma unroll
            for (int j = 0; j < 4; ++j) { h0[j] = (f16)0.0f; h1[j] = (f16)0.0f; }
        }
        *(f16x4*)(wp + wr_p) = h0;
        *(f16x4*)(wp + wr_m) = h1;
    };

    // ---- prologue: fold tile 0, issue tile-1 loads ----
    fold_write(lds, true);
    {
        const uint base = (uint)(WTILE * HOP * 4);
        fv = load4u(xrow + (voff_f + base));
        rv = load4u(xrow + (voff_r + base));
    }
    asm volatile("s_waitcnt lgkmcnt(0)" ::: "memory");
    __builtin_amdgcn_s_barrier();
    asm volatile("" ::: "memory");

    float ssum0 = 0.f, ssum1 = 0.f;
    const uint vclamp = (uint)((NS - 4) * 4);

    for (int mt = 0; mt < NT; ++mt) {
        const char* ap = lds + ((mt & 1) << 13);

        f32x4 acc0 = {0,0,0,0}, acc1 = {0,0,0,0};
        __builtin_amdgcn_s_setprio(1);
        #pragma unroll
        for (int kk = 0; kk < 4; ++kk) {
            const f16x8 af = *(const f16x8*)(ap + rd[kk]);
            acc0 = __builtin_amdgcn_mfma_f32_16x16x32_f16(af, bfrag[0][kk], acc0, 0, 0, 0);
            acc1 = __builtin_amdgcn_mfma_f32_16x16x32_f16(af, bfrag[1][kk], acc1, 0, 0, 0);
        }
        __builtin_amdgcn_s_setprio(0);
        #pragma unroll
        for (int r = 0; r < 4; ++r) {
            ssum0 += acc0[r] * acc0[r];
            ssum1 += acc1[r] * acc1[r];
        }

        if (mt < NT - 1) {
            // fold+write tile mt+1 (loads issued one iteration ago)
            char* wp = lds + (((mt + 1) & 1) << 13);
            const bool valid = (mt != 15) || (sw == 0);  // tile 16: only window 256
            fold_write(wp, valid);
            if (mt < NT - 2) {   // issue loads for tile mt+2; stay in flight across barrier
                const uint base = (uint)((mt + 2) * WTILE * HOP * 4);
                fv = load4u(xrow + min(voff_f + base, vclamp));
                rv = load4u(xrow + min(voff_r + base, vclamp));
            }
            asm volatile("s_waitcnt lgkmcnt(0)" ::: "memory");  // drain ds ops only
            __builtin_amdgcn_s_barrier();
            asm volatile("" ::: "memory");
        }
    }

    // ---- reduce over k-groups (D col = lane&15); one owner wave per comp ----
    {
        float v = ssum0;
        v += __shfl_xor(v, 16, 64);
        v += __shfl_xor(v, 32, 64);
        if (kg == 0) scol[is_sin * 128 + (cq & 3) * 32 + r16] = v;
        float w = ssum1;
        w += __shfl_xor(w, 16, 64);
        w += __shfl_xor(w, 32, 64);
        if (kg == 0) scol[is_sin * 128 + (cq & 3) * 32 + 16 + r16] = w;
    }
    __syncthreads();
    if (tid < NB) {
        out[(size_t)row * NB + tid] = (scol[tid] + scol[tid + NB]) * (1.0f / 257.0f);
    }
}

extern "C" void kernel_launch(void* const* d_in, const int* in_sizes, int n_in,
                              void* d_out, int out_size, void* d_ws, size_t ws_size,
                              hipStream_t stream) {
    const float* X = (const float*)d_in[0];
    float* out = (float*)d_out;
    (void)in_sizes; (void)n_in; (void)d_ws; (void)ws_size; (void)out_size;
    psd_kernel<<<dim3(NROWS), dim3(512), 0, stream>>>(X, out);
}

// Round 8
// 53.512 us; speedup vs baseline: 4.0455x; 1.1318x over previous
//
#include <hip/hip_runtime.h>
#include <hip/hip_bf16.h>

#define NS     32768
#define NROWS  2048
#define HOP    127
#define NW     257
#define NB     128
#define WTILE  16
#define NT     17            // ceil(257/16); tile 16 has 1 valid window
#define TWOPI_255 0.02463994236f   // 2*pi/255

typedef _Float16 f16;
typedef __attribute__((ext_vector_type(2))) _Float16 f16x2;
typedef __attribute__((ext_vector_type(4))) _Float16 f16x4;
typedef __attribute__((ext_vector_type(8))) _Float16 f16x8;
typedef __attribute__((ext_vector_type(4))) float f32x4;

__device__ inline f32x4 load4u(const char* p) {  // 4B-aligned 16B load
    f32x4 v;
    __builtin_memcpy(&v, p, 16);
    return v;
}

// ---------------------------------------------------------------------------
// Kernel 1: build the folded-DFT basis table (64 KB) in fragment order.
// Fragment fi (0..63) = cq*8 + nt*4 + kk; lane l holds f16x8 for
// comp = (cq>>2)*128 + (cq&3)*32 + nt*16 + (l&15), k = kk*32 + (l>>4)*8 + j.
// The same table serves every row-block (basis is row-independent).
// ---------------------------------------------------------------------------
__global__ __launch_bounds__(256)
void basis_kernel(f16* __restrict__ bt) {
    const int t  = blockIdx.x * 256 + threadIdx.x;   // 0..4095
    const int fi = t >> 6;
    const int l  = t & 63;
    const int cq = fi >> 3;
    const int nt = (fi >> 2) & 1;
    const int kk = fi & 3;
    const int is_sin = cq >> 2;
    const int f  = (cq & 3) * 32 + nt * 16 + (l & 15);   // freq 0..127
    int m = (f * (kk * 32 + (l >> 4) * 8)) % 255;
    f16x8 v;
    #pragma unroll
    for (int j = 0; j < 8; ++j) {
        const float ang = (float)m * TWOPI_255;
        v[j] = (f16)(is_sin ? __sinf(ang) : __cosf(ang));
        m += f; if (m >= 255) m -= 255;
    }
    *(f16x8*)(bt + (size_t)t * 8) = v;   // 16B/thread, coalesced
}

// ---------------------------------------------------------------------------
// Kernel 2: one block (8 waves, 512 thr) per row. Wave cq owns 32 comps.
// K folded 255->128: y+[k]=x[k]+x[255-k], y-[k]=x[k]-x[255-k];
// S[f] = (sum_w Ccos^2 + Csin^2)/257. Basis loaded from bt (L2-resident).
// ---------------------------------------------------------------------------
__global__ __launch_bounds__(512, 6)
void psd_kernel(const float* __restrict__ X, const f16* __restrict__ bt,
                float* __restrict__ out) {
    const int row  = blockIdx.x;
    const int tid  = threadIdx.x;
    const int lane = tid & 63;
    const int cq   = tid >> 6;      // wave 0..7
    const int r16  = lane & 15;
    const int kg   = lane >> 4;
    const int is_sin = cq >> 2;     // waves 4..7 -> sin half

    __shared__ alignas(16) f16 atile[2][WTILE * 256];  // 2 x 8 KB, XOR-swizzled
    __shared__ float scol[256];

    const char* __restrict__ xrow = (const char*)(X + (size_t)row * NS);

    const int sw  = tid >> 5;           // staging window 0..15
    const int sq  = tid & 31;           // staging k-quad 0..31
    const int sk0 = sq * 4;

    // loop-invariant per-lane global byte offsets (tile-local)
    const uint voff_f = (uint)((sw * HOP + sk0) * 4);
    const uint voff_r = (uint)((sw * HOP + 252 - sk0) * 4);

    // ---- tile-0 staging loads ----
    f32x4 fv = load4u(xrow + voff_f);
    f32x4 rv = load4u(xrow + voff_r);

    // ---- load basis fragments (8 coalesced dwordx4; shared across all blocks) ----
    f16x8 bfrag[2][4];
    {
        const char* bp = (const char*)bt + (uint)(cq * 8192 + lane * 16);
        #pragma unroll
        for (int nt = 0; nt < 2; ++nt)
            #pragma unroll
            for (int kk = 0; kk < 4; ++kk)
                bfrag[nt][kk] = *(const f16x8*)(bp + (uint)((nt * 4 + kk) * 1024));
    }

    char* const lds = (char*)&atile[0][0];

    // hoisted LDS byte offsets
    const uint swz  = (uint)((sw & 7) << 4);
    const uint wr_p = ((uint)(sw * 512 + sq * 8)) ^ swz;         // y+ (8B)
    const uint wr_m = ((uint)(sw * 512 + sq * 8 + 256)) ^ swz;   // y- (8B)
    const uint rswz = (uint)((r16 & 7) << 4);
    uint rd[4];
    #pragma unroll
    for (int kk = 0; kk < 4; ++kk)
        rd[kk] = ((uint)(r16 * 512 + is_sin * 256 + kg * 16 + kk * 64)) ^ rswz;

    // ---- packed fold (4 pairs) + 2 x ds_write_b64 ----
    auto fold_write = [&](char* wp, bool valid) {
        // partner of k=sk0+j is rv[3-j]
        const f16x2 fp01 = __builtin_bit_cast(f16x2, __builtin_amdgcn_cvt_pkrtz(fv[0], fv[1]));
        const f16x2 fp23 = __builtin_bit_cast(f16x2, __builtin_amdgcn_cvt_pkrtz(fv[2], fv[3]));
        const f16x2 rp01 = __builtin_bit_cast(f16x2, __builtin_amdgcn_cvt_pkrtz(rv[3], rv[2]));
        const f16x2 rp23 = __builtin_bit_cast(f16x2, __builtin_amdgcn_cvt_pkrtz(rv[1], rv[0]));
        const f16x2 yp01 = fp01 + rp01, yp23 = fp23 + rp23;
        const f16x2 ym01 = fp01 - rp01, ym23 = fp23 - rp23;
        f16x4 h0, h1;
        h0[0] = yp01[0]; h0[1] = yp01[1]; h0[2] = yp23[0]; h0[3] = yp23[1];
        h1[0] = ym01[0]; h1[1] = ym01[1]; h1[2] = ym23[0]; h1[3] = ym23[1];
        if (sq == 0) { h0[0] = (f16)fv[0]; h1[0] = (f16)0.0f; }  // k=0: pad partner
        if (!valid) {
            #pragma unroll
            for (int j = 0; j < 4; ++j) { h0[j] = (f16)0.0f; h1[j] = (f16)0.0f; }
        }
        *(f16x4*)(wp + wr_p) = h0;
        *(f16x4*)(wp + wr_m) = h1;
    };

    // ---- prologue: fold tile 0, issue tile-1 loads ----
    fold_write(lds, true);
    {
        const uint base = (uint)(WTILE * HOP * 4);
        fv = load4u(xrow + (voff_f + base));
        rv = load4u(xrow + (voff_r + base));
    }
    asm volatile("s_waitcnt lgkmcnt(0)" ::: "memory");
    __builtin_amdgcn_s_barrier();
    asm volatile("" ::: "memory");

    float ssum0 = 0.f, ssum1 = 0.f;
    const uint vclamp = (uint)((NS - 4) * 4);

    for (int mt = 0; mt < NT; ++mt) {
        const char* ap = lds + ((mt & 1) << 13);

        f32x4 acc0 = {0,0,0,0}, acc1 = {0,0,0,0};
        __builtin_amdgcn_s_setprio(1);
        #pragma unroll
        for (int kk = 0; kk < 4; ++kk) {
            const f16x8 af = *(const f16x8*)(ap + rd[kk]);
            acc0 = __builtin_amdgcn_mfma_f32_16x16x32_f16(af, bfrag[0][kk], acc0, 0, 0, 0);
            acc1 = __builtin_amdgcn_mfma_f32_16x16x32_f16(af, bfrag[1][kk], acc1, 0, 0, 0);
        }
        __builtin_amdgcn_s_setprio(0);
        #pragma unroll
        for (int r = 0; r < 4; ++r) {
            ssum0 += acc0[r] * acc0[r];
            ssum1 += acc1[r] * acc1[r];
        }

        if (mt < NT - 1) {
            // fold+write tile mt+1 (loads issued one iteration ago)
            char* wp = lds + (((mt + 1) & 1) << 13);
            const bool valid = (mt != 15) || (sw == 0);  // tile 16: only window 256
            fold_write(wp, valid);
            if (mt < NT - 2) {   // issue loads for tile mt+2; in flight across barrier
                const uint base = (uint)((mt + 2) * WTILE * HOP * 4);
                fv = load4u(xrow + min(voff_f + base, vclamp));
                rv = load4u(xrow + min(voff_r + base, vclamp));
            }
            asm volatile("s_waitcnt lgkmcnt(0)" ::: "memory");  // drain ds ops only
            __builtin_amdgcn_s_barrier();
            asm volatile("" ::: "memory");
        }
    }

    // ---- reduce over k-groups (D col = lane&15); one owner wave per comp ----
    {
        float v = ssum0;
        v += __shfl_xor(v, 16, 64);
        v += __shfl_xor(v, 32, 64);
        if (kg == 0) scol[is_sin * 128 + (cq & 3) * 32 + r16] = v;
        float w = ssum1;
        w += __shfl_xor(w, 16, 64);
        w += __shfl_xor(w, 32, 64);
        if (kg == 0) scol[is_sin * 128 + (cq & 3) * 32 + 16 + r16] = w;
    }
    __syncthreads();
    if (tid < NB) {
        out[(size_t)row * NB + tid] = (scol[tid] + scol[tid + NB]) * (1.0f / 257.0f);
    }
}

extern "C" void kernel_launch(void* const* d_in, const int* in_sizes, int n_in,
                              void* d_out, int out_size, void* d_ws, size_t ws_size,
                              hipStream_t stream) {
    const float* X = (const float*)d_in[0];
    float* out = (float*)d_out;
    f16* bt = (f16*)d_ws;   // 64 KB basis table
    (void)in_sizes; (void)n_in; (void)ws_size; (void)out_size;
    basis_kernel<<<dim3(16), dim3(256), 0, stream>>>(bt);
    psd_kernel<<<dim3(NROWS), dim3(512), 0, stream>>>(X, bt, out);
}